// Round 12
// baseline (150.974 us; speedup 1.0000x reference)
//
#include <hip/hip_runtime.h>
#include <hip/hip_bf16.h>

#define DIM 768
#define QKVD 2304      // 3*DIM
#define NHEADS 12
#define NTOK 197
#define NP 208         // padded tokens (13*16)
#define NPS 232        // VT / P LDS row stride in shorts
#define M_ROWS 12608   // B*N
#define M_PAD 12800    // 100*128
#define HEADS_TOT 768  // B*H
#define NT 24          // K-tiles of 32 (768/32)

typedef __attribute__((ext_vector_type(8))) short bf16x8;
typedef __attribute__((ext_vector_type(4))) float f32x4;

__device__ inline short f2bf(float f) {
  union { __hip_bfloat16 h; short s; } u;
  u.h = __float2bfloat16(f);
  return u.s;
}

__device__ __forceinline__ void gload16(const short* g, short* l) {
  __builtin_amdgcn_global_load_lds((const __attribute__((address_space(1))) void*)g,
                                   (__attribute__((address_space(3))) void*)l, 16, 0, 0);
}

// bijective XCD-aware swizzle (m204)
__device__ __forceinline__ int xcd_swz(int orig, int nwg) {
  int q = nwg >> 3, r = nwg & 7;
  int x = orig & 7, p = orig >> 3;
  return (x < r ? x * (q + 1) : r * (q + 1) + (x - r) * q) + p;
}

// ---------------- prep: fp32->bf16 converts + xb pad zero + rpb expansion (fused) ----------------
__global__ void prep_kernel(const float* __restrict__ x, const float* __restrict__ wq,
                            const float* __restrict__ wp, const float* __restrict__ table,
                            short* __restrict__ xb, short* __restrict__ wqb,
                            short* __restrict__ wpb, float* __restrict__ rpbf) {
  int idx = blockIdx.x * 256 + threadIdx.x;
  const int n_x  = M_ROWS * DIM / 4;
  const int n_wq = 3 * DIM * DIM / 4;
  const int n_wp = DIM * DIM / 4;
  const int n_pad = (M_PAD - M_ROWS) * DIM / 4;
  const int conv_tot = n_x + n_wq + n_wp + n_pad;
  if (idx < conv_tot) {
    if (idx >= n_x + n_wq + n_wp) {
      int k = idx - n_x - n_wq - n_wp;
      short4 z = {0, 0, 0, 0};
      *(short4*)(xb + (size_t)M_ROWS * DIM + (size_t)k * 4) = z;
      return;
    }
    const float4* src; short* dst; int off;
    if (idx < n_x)             { src = (const float4*)x;  dst = xb;  off = idx; }
    else if (idx < n_x + n_wq) { src = (const float4*)wq; dst = wqb; off = idx - n_x; }
    else                       { src = (const float4*)wp; dst = wpb; off = idx - n_x - n_wq; }
    float4 v = src[off];
    short4 o;
    o.x = f2bf(v.x); o.y = f2bf(v.y); o.z = f2bf(v.z); o.w = f2bf(v.w);
    *(short4*)(dst + (size_t)off * 4) = o;
    return;
  }
  int ridx = idx - conv_tot;
  if (ridx >= NHEADS * NP * NP) return;
  int h = ridx / (NP * NP);
  int rem = ridx - h * NP * NP;
  int i = rem / NP;
  int j = rem - i * NP;
  float v = 0.f;
  if (i < NTOK && j < NTOK) {
    int t;
    if (i == 0 && j == 0) t = 731;
    else if (i == 0)      t = 729;
    else if (j == 0)      t = 730;
    else {
      int p = i - 1, q = j - 1;
      int ri = p / 14, ci = p - ri * 14;
      int rj = q / 14, cj = q - rj * 14;
      t = (ri - rj + 13) * 27 + (ci - cj + 13);
    }
    v = table[t * NHEADS + h];
  }
  rpbf[ridx] = v;
}

// ======== 128x128 ring GEMM core (4-deep, 256 threads, 64KB LDS -> 2 blocks/CU) ========
__device__ __forceinline__ void tile_step128(int kt, short* lds,
                                             const short* Asrc, const short* Bsrc, short* sdst,
                                             int aoff, int boff,
                                             bf16x8 (&afc)[4], bf16x8 (&bfc)[4],
                                             bf16x8 (&afn)[4], bf16x8 (&bfn)[4],
                                             f32x4 (&acc)[4][4]) {
  const bool stg = (kt < NT - 3);
  const bool pre = (kt < NT - 1);
  const short* nb = lds + ((kt + 1) & 3) * 8192;
  short* stgd = sdst + ((kt + 3) & 3) * 8192;
  const int kc = (kt + 3) * 32;
  if (stg) { gload16(Asrc + kc, stgd); gload16(Bsrc + kc, stgd + 4096); }
  if (pre) {
#pragma unroll
    for (int n = 0; n < 4; ++n) bfn[n] = *(const bf16x8*)(nb + boff + n * 512);
#pragma unroll
    for (int j = 0; j < 2; ++j) afn[j] = *(const bf16x8*)(nb + aoff + j * 512);
  }
  __builtin_amdgcn_s_setprio(1);
#pragma unroll
  for (int j = 0; j < 2; ++j)
#pragma unroll
    for (int n = 0; n < 4; ++n)
      acc[j][n] = __builtin_amdgcn_mfma_f32_16x16x32_bf16(afc[j], bfc[n], acc[j][n], 0, 0, 0);
  __builtin_amdgcn_s_setprio(0);
  if (stg) { gload16(Asrc + (size_t)64 * DIM + kc, stgd + 2048);
             gload16(Bsrc + (size_t)64 * DIM + kc, stgd + 4096 + 2048); }
  if (pre) {
#pragma unroll
    for (int j = 2; j < 4; ++j) afn[j] = *(const bf16x8*)(nb + aoff + j * 512);
  }
  __builtin_amdgcn_s_setprio(1);
#pragma unroll
  for (int j = 2; j < 4; ++j)
#pragma unroll
    for (int n = 0; n < 4; ++n)
      acc[j][n] = __builtin_amdgcn_mfma_f32_16x16x32_bf16(afc[j], bfc[n], acc[j][n], 0, 0, 0);
  __builtin_amdgcn_s_setprio(0);
  if (kt < NT - 3)       { asm volatile("s_waitcnt vmcnt(4)" ::: "memory"); }
  else if (kt == NT - 3) { asm volatile("s_waitcnt vmcnt(0)" ::: "memory"); }
  __builtin_amdgcn_s_barrier();
}

__device__ __forceinline__ void ring128_mainloop(const short* __restrict__ A,
                                                 const short* __restrict__ Bw,
                                                 int tm, int tn, short* lds,
                                                 f32x4 (&acc)[4][4]) {
  const int tid = threadIdx.x;
  const int srow = tid >> 2;
  const int sslot = ((tid & 3) - (tid >> 3)) & 3;
  const int l = tid & 63, lr = l & 15, lg = l >> 4;
  const int w = tid >> 6, wm = w >> 1, wn = w & 1;
  const short* Asrc = A + (size_t)(tm * 128 + srow) * DIM + sslot * 8;
  const short* Bsrc = Bw + (size_t)(tn * 128 + srow) * DIM + sslot * 8;
  short* sdst = lds + tid * 8;
  const int slotR = (lg + (lr >> 1)) & 3;
  const int aoff = wm * 2048 + lr * 32 + slotR * 8;
  const int boff = 4096 + wn * 2048 + lr * 32 + slotR * 8;
#pragma unroll
  for (int m = 0; m < 4; ++m)
#pragma unroll
    for (int n = 0; n < 4; ++n) { f32x4 z = {0.f, 0.f, 0.f, 0.f}; acc[m][n] = z; }

#pragma unroll
  for (int kt = 0; kt < 3; ++kt) {
    gload16(Asrc + kt * 32, sdst + kt * 8192);
    gload16(Bsrc + kt * 32, sdst + kt * 8192 + 4096);
    gload16(Asrc + (size_t)64 * DIM + kt * 32, sdst + kt * 8192 + 2048);
    gload16(Bsrc + (size_t)64 * DIM + kt * 32, sdst + kt * 8192 + 4096 + 2048);
  }
  asm volatile("s_waitcnt vmcnt(4)" ::: "memory");
  __builtin_amdgcn_s_barrier();

  bf16x8 afA[4], bfA[4], afB[4], bfB[4];
#pragma unroll
  for (int n = 0; n < 4; ++n) bfA[n] = *(const bf16x8*)(lds + boff + n * 512);
#pragma unroll
  for (int j = 0; j < 4; ++j) afA[j] = *(const bf16x8*)(lds + aoff + j * 512);

  for (int kt = 0; kt < NT; kt += 2) {
    tile_step128(kt,     lds, Asrc, Bsrc, sdst, aoff, boff, afA, bfA, afB, bfB, acc);
    tile_step128(kt + 1, lds, Asrc, Bsrc, sdst, aoff, boff, afB, bfB, afA, bfA, acc);
  }
  __builtin_amdgcn_s_barrier();   // all frag reads done before LDS reuse in epilogue
}

// ---------------- QKV GEMM: 128^2 ring, bias+scale, LDS-staged bf16 coalesced epilogue ----------------
__global__ __launch_bounds__(256, 2)
void gemm_qkv_kernel(const short* __restrict__ xb, const short* __restrict__ wqb,
                     const float* __restrict__ q_bias, const float* __restrict__ v_bias,
                     short* __restrict__ qkvb) {
  __shared__ __attribute__((aligned(16))) short lds[32768];   // 64 KB
  const int wg = xcd_swz(blockIdx.x, 100 * 18);
  const int tn = wg % 18, tm = wg / 18;   // tn fastest: A-tile L2 reuse
  f32x4 acc[4][4];
  ring128_mainloop(xb, wqb, tm, tn, lds, acc);

  const int tid = threadIdx.x;
  const int w = tid >> 6, wm = w >> 1, wn = w & 1;
  const int l = tid & 63, lr = l & 15, lg = l >> 4;
  for (int p = 0; p < 2; ++p) {      // 64-row halves of the 128-row tile
    if (wm == p) {
#pragma unroll
      for (int n = 0; n < 4; ++n) {
        int c = tn * 128 + wn * 64 + n * 16 + lr;
        int part = (c < 768) ? 0 : ((c < 1536) ? 1 : 2);
        float bias = (part == 0) ? q_bias[c] : ((part == 2) ? v_bias[c - 1536] : 0.f);
        float scl = (part == 0) ? 0.125f : 1.f;
#pragma unroll
        for (int m = 0; m < 4; ++m)
#pragma unroll
          for (int i = 0; i < 4; ++i)
            lds[(m * 16 + lg * 4 + i) * 136 + wn * 64 + n * 16 + lr] =
                f2bf((acc[m][n][i] + bias) * scl);
      }
    }
    __syncthreads();
#pragma unroll
    for (int k = 0; k < 4; ++k) {    // 64 rows x 16 chunks of bf16x8 = 1024 / 256 threads
      int chunk = tid + k * 256;
      int row = chunk >> 4, ch = chunk & 15;
      bf16x8 v = *(const bf16x8*)(lds + row * 136 + ch * 8);
      *(bf16x8*)(qkvb + (size_t)(tm * 128 + p * 64 + row) * QKVD + tn * 128 + ch * 8) = v;
    }
    __syncthreads();
  }
}

// ---------------- proj GEMM: same ring, fp32 out + bias, LDS-staged epilogue ----------------
__global__ __launch_bounds__(256, 2)
void gemm_proj_kernel(const short* __restrict__ ab, const short* __restrict__ wpb,
                      const float* __restrict__ proj_bias, float* __restrict__ out) {
  __shared__ __attribute__((aligned(16))) short lds[32768];   // 64 KB
  const int wg = xcd_swz(blockIdx.x, 99 * 6);
  const int tn = wg % 6, tm = wg / 6;
  f32x4 acc[4][4];
  ring128_mainloop(ab, wpb, tm, tn, lds, acc);

  const int tid = threadIdx.x;
  const int w = tid >> 6, wm = w >> 1, wn = w & 1;
  const int l = tid & 63, lr = l & 15, lg = l >> 4;
  float* ldsF = (float*)lds;
  for (int p = 0; p < 2; ++p) {
    if (wm == p) {
#pragma unroll
      for (int n = 0; n < 4; ++n) {
        int c = tn * 128 + wn * 64 + n * 16 + lr;
        float pb = proj_bias[c];
#pragma unroll
        for (int m = 0; m < 4; ++m)
#pragma unroll
          for (int i = 0; i < 4; ++i)
            ldsF[(m * 16 + lg * 4 + i) * 132 + wn * 64 + n * 16 + lr] = acc[m][n][i] + pb;
      }
    }
    __syncthreads();
#pragma unroll
    for (int k = 0; k < 8; ++k) {    // 64 rows x 32 chunks of f32x4 = 2048 / 256 threads
      int chunk = tid + k * 256;
      int row = chunk >> 5, ch = chunk & 31;
      int r = tm * 128 + p * 64 + row;
      if (r < M_ROWS) {
        f32x4 v = *(const f32x4*)(ldsF + row * 132 + ch * 4);
        *(f32x4*)(out + (size_t)r * DIM + tn * 128 + ch * 4) = v;
      }
    }
    __syncthreads();
  }
}

// ---------------- attention (round-10 verbatim): 8 waves/block, reads qkvb directly ----------------
__global__ __launch_bounds__(512, 1)
void attn_kernel(const short* __restrict__ qkvb, const float* __restrict__ rpbf,
                 short* __restrict__ aout) {
  __shared__ __attribute__((aligned(16))) short Klds[208 * 64];
  __shared__ __attribute__((aligned(16))) short Vlds[64 * NPS];
  __shared__ __attribute__((aligned(16))) short Plds[8 * 16 * NPS];
  const int bh = blockIdx.x;
  const int b = bh / 12, h = bh - b * 12;
  const short* base = qkvb + (size_t)(b * 197) * QKVD;
  const short* Qg = base + h * 64;
  const short* Kg = base + 768 + h * 64;
  const short* Vg = base + 1536 + h * 64;
  const float* RP = rpbf + (size_t)h * NP * NP;
  const int tid = threadIdx.x;
  const int wave = tid >> 6, l = tid & 63, lr = l & 15, lg = l >> 4;

  for (int c = tid; c < 1664; c += 512) {
    int r = c >> 3, sp = c & 7;
    int rr = r < NTOK ? r : NTOK - 1;
    gload16(Kg + (size_t)rr * QKVD + ((sp ^ (r & 7)) << 3), Klds + c * 8);
  }
  for (int idx = tid; idx < 64 * NP; idx += 512) {
    int t = idx >> 6, d = idx & 63;
    int tt = t < NTOK ? t : NTOK - 1;
    Vlds[d * NPS + t] = Vg[(size_t)tt * QKVD + d];
  }
  __syncthreads();
  if (tid < 64) {
    for (int j = NP; j < NPS; ++j) Vlds[tid * NPS + j] = 0;
  }
  __syncthreads();

  short* Pw = Plds + wave * 16 * NPS;
  for (int s = wave; s < 13; s += 8) {
    const int row0 = s * 16;
    const int qrow = (row0 + lr < NTOK) ? (row0 + lr) : (NTOK - 1);
    bf16x8 qf0 = *(const bf16x8*)(Qg + (size_t)qrow * QKVD + lg * 8);
    bf16x8 qf1 = *(const bf16x8*)(Qg + (size_t)qrow * QKVD + 32 + lg * 8);
    f32x4 acc[13];
#pragma unroll
    for (int t = 0; t < 13; ++t) { f32x4 z = {0.f, 0.f, 0.f, 0.f}; acc[t] = z; }
    __builtin_amdgcn_s_setprio(1);
#pragma unroll
    for (int t = 0; t < 13; ++t) {
      int rk = t * 16 + lr;
      int sw = lr & 7;
      bf16x8 kf0 = *(const bf16x8*)(Klds + rk * 64 + ((lg ^ sw) << 3));
      bf16x8 kf1 = *(const bf16x8*)(Klds + rk * 64 + (((4 + lg) ^ sw) << 3));
      acc[t] = __builtin_amdgcn_mfma_f32_16x16x32_bf16(qf0, kf0, acc[t], 0, 0, 0);
      acc[t] = __builtin_amdgcn_mfma_f32_16x16x32_bf16(qf1, kf1, acc[t], 0, 0, 0);
    }
    __builtin_amdgcn_s_setprio(0);
    float sum4[4];
#pragma unroll
    for (int i = 0; i < 4; ++i) {
      const int row = row0 + lg * 4 + i;
      const float* rp = RP + (size_t)row * NP;
      float sv[13];
      float mx = -3e38f;
#pragma unroll
      for (int t = 0; t < 13; ++t) {
        int col = t * 16 + lr;
        float s_ = (col < NTOK) ? (acc[t][i] + rp[col]) : -3e38f;
        sv[t] = s_;
        mx = fmaxf(mx, s_);
      }
      mx = fmaxf(mx, __shfl_xor(mx, 1, 16));
      mx = fmaxf(mx, __shfl_xor(mx, 2, 16));
      mx = fmaxf(mx, __shfl_xor(mx, 4, 16));
      mx = fmaxf(mx, __shfl_xor(mx, 8, 16));
      float sm = 0.f;
#pragma unroll
      for (int t = 0; t < 13; ++t) {
        float p = __expf(sv[t] - mx);
        sm += p;
        Pw[(lg * 4 + i) * NPS + t * 16 + lr] = f2bf(p);
      }
      sm += __shfl_xor(sm, 1, 16);
      sm += __shfl_xor(sm, 2, 16);
      sm += __shfl_xor(sm, 4, 16);
      sm += __shfl_xor(sm, 8, 16);
      sum4[i] = sm;
      Pw[(lg * 4 + i) * NPS + 208 + lr] = 0;
    }
    f32x4 o[4];
#pragma unroll
    for (int dt = 0; dt < 4; ++dt) { f32x4 z = {0.f, 0.f, 0.f, 0.f}; o[dt] = z; }
    __builtin_amdgcn_s_setprio(1);
#pragma unroll
    for (int jb = 0; jb < 7; ++jb) {
      bf16x8 pf = *(const bf16x8*)(Pw + lr * NPS + jb * 32 + lg * 8);
#pragma unroll
      for (int dt = 0; dt < 4; ++dt) {
        bf16x8 vf = *(const bf16x8*)(Vlds + (dt * 16 + lr) * NPS + jb * 32 + lg * 8);
        o[dt] = __builtin_amdgcn_mfma_f32_16x16x32_bf16(pf, vf, o[dt], 0, 0, 0);
      }
    }
    __builtin_amdgcn_s_setprio(0);
#pragma unroll
    for (int i = 0; i < 4; ++i) {
      const int row = row0 + lg * 4 + i;
      if (row < NTOK) {
        float inv = 1.f / sum4[i];
        size_t base2 = (size_t)(b * 197 + row) * DIM + h * 64;
#pragma unroll
        for (int dt = 0; dt < 4; ++dt)
          aout[base2 + dt * 16 + lr] = f2bf(o[dt][i] * inv);
      }
    }
  }
}

extern "C" void kernel_launch(void* const* d_in, const int* in_sizes, int n_in,
                              void* d_out, int out_size, void* d_ws, size_t ws_size,
                              hipStream_t stream) {
  const float* x         = (const float*)d_in[0];
  const float* wqkv      = (const float*)d_in[1];
  const float* q_bias    = (const float*)d_in[2];
  const float* v_bias    = (const float*)d_in[3];
  const float* table     = (const float*)d_in[4];
  const float* wproj     = (const float*)d_in[5];
  const float* proj_bias = (const float*)d_in[6];
  float* out = (float*)d_out;

  char* p = (char*)d_ws;
  short* xb    = (short*)p; p += (size_t)M_PAD * DIM * 2;
  short* wqb   = (short*)p; p += (size_t)3 * DIM * DIM * 2;
  short* wpb   = (short*)p; p += (size_t)DIM * DIM * 2;
  short* qkvb  = (short*)p; p += (size_t)M_PAD * QKVD * 2;
  float* rpbf  = (float*)p; p += (size_t)NHEADS * NP * NP * 4;
  short* aout  = xb;  // reuse: xb is dead after gemm_qkv (pad rows stay zero)

  const int conv_tot = (M_ROWS * DIM + 3 * DIM * DIM + DIM * DIM + (M_PAD - M_ROWS) * DIM) / 4;
  const int prep_tot = conv_tot + NHEADS * NP * NP;
  prep_kernel<<<(prep_tot + 255) / 256, 256, 0, stream>>>(x, wqkv, wproj, table, xb, wqb, wpb, rpbf);
  gemm_qkv_kernel<<<100 * 18, 256, 0, stream>>>(xb, wqb, q_bias, v_bias, qkvb);
  attn_kernel<<<HEADS_TOT, 512, 0, stream>>>(qkvb, rpbf, aout);
  gemm_proj_kernel<<<99 * 6, 256, 0, stream>>>(aout, wpb, proj_bias, out);
}

// Round 13
// 143.001 us; speedup vs baseline: 1.0558x; 1.0558x over previous
//
#include <hip/hip_runtime.h>
#include <hip/hip_bf16.h>

#define DIM 768
#define QKVD 2304      // 3*DIM
#define NHEADS 12
#define NTOK 197
#define NP 208         // padded tokens (13*16)
#define NPS 232        // VT / P LDS row stride in shorts
#define M_ROWS 12608   // B*N
#define M_PAD 12800    // 100*128 = 50*256
#define HEADS_TOT 768  // B*H
#define NT 24          // K-tiles of 32 (768/32)

typedef __attribute__((ext_vector_type(8))) short bf16x8;
typedef __attribute__((ext_vector_type(4))) float f32x4;

__device__ inline short f2bf(float f) {
  union { __hip_bfloat16 h; short s; } u;
  u.h = __float2bfloat16(f);
  return u.s;
}

__device__ __forceinline__ void gload16(const short* g, short* l) {
  __builtin_amdgcn_global_load_lds((const __attribute__((address_space(1))) void*)g,
                                   (__attribute__((address_space(3))) void*)l, 16, 0, 0);
}

// bijective XCD-aware swizzle (m204)
__device__ __forceinline__ int xcd_swz(int orig, int nwg) {
  int q = nwg >> 3, r = nwg & 7;
  int x = orig & 7, p = orig >> 3;
  return (x < r ? x * (q + 1) : r * (q + 1) + (x - r) * q) + p;
}

// ---------------- prep: fp32->bf16 converts + xb pad zero + rpb expansion (fused) ----------------
__global__ void prep_kernel(const float* __restrict__ x, const float* __restrict__ wq,
                            const float* __restrict__ wp, const float* __restrict__ table,
                            short* __restrict__ xb, short* __restrict__ wqb,
                            short* __restrict__ wpb, float* __restrict__ rpbf) {
  int idx = blockIdx.x * 256 + threadIdx.x;
  const int n_x  = M_ROWS * DIM / 4;
  const int n_wq = 3 * DIM * DIM / 4;
  const int n_wp = DIM * DIM / 4;
  const int n_pad = (M_PAD - M_ROWS) * DIM / 4;
  const int conv_tot = n_x + n_wq + n_wp + n_pad;
  if (idx < conv_tot) {
    if (idx >= n_x + n_wq + n_wp) {
      int k = idx - n_x - n_wq - n_wp;
      short4 z = {0, 0, 0, 0};
      *(short4*)(xb + (size_t)M_ROWS * DIM + (size_t)k * 4) = z;
      return;
    }
    const float4* src; short* dst; int off;
    if (idx < n_x)             { src = (const float4*)x;  dst = xb;  off = idx; }
    else if (idx < n_x + n_wq) { src = (const float4*)wq; dst = wqb; off = idx - n_x; }
    else                       { src = (const float4*)wp; dst = wpb; off = idx - n_x - n_wq; }
    float4 v = src[off];
    short4 o;
    o.x = f2bf(v.x); o.y = f2bf(v.y); o.z = f2bf(v.z); o.w = f2bf(v.w);
    *(short4*)(dst + (size_t)off * 4) = o;
    return;
  }
  int ridx = idx - conv_tot;
  if (ridx >= NHEADS * NP * NP) return;
  int h = ridx / (NP * NP);
  int rem = ridx - h * NP * NP;
  int i = rem / NP;
  int j = rem - i * NP;
  float v = 0.f;
  if (i < NTOK && j < NTOK) {
    int t;
    if (i == 0 && j == 0) t = 731;
    else if (i == 0)      t = 729;
    else if (j == 0)      t = 730;
    else {
      int p = i - 1, q = j - 1;
      int ri = p / 14, ci = p - ri * 14;
      int rj = q / 14, cj = q - rj * 14;
      t = (ri - rj + 13) * 27 + (ci - cj + 13);
    }
    v = table[t * NHEADS + h];
  }
  rpbf[ridx] = v;
}

// ================= 256x256 ring GEMM (round-10 proven: 57us, 0 conflicts) =================
__device__ __forceinline__ void tile_step(int kt, short* lds,
                                          const short* Asrc, const short* Bsrc, short* sdst,
                                          int aoff, int boff,
                                          bf16x8 (&afc)[8], bf16x8 (&bfc)[4],
                                          bf16x8 (&afn)[8], bf16x8 (&bfn)[4],
                                          f32x4 (&acc)[8][4]) {
  const bool stg = (kt < NT - 3);
  const bool pre = (kt < NT - 1);
  const short* nb = lds + ((kt + 1) & 3) * 16384;
  short* stgd = sdst + ((kt + 3) & 3) * 16384;
  const int kc = (kt + 3) * 32;
  if (stg) { gload16(Asrc + kc, stgd); gload16(Bsrc + kc, stgd + 8192); }
  if (pre) {
#pragma unroll
    for (int n = 0; n < 4; ++n) bfn[n] = *(const bf16x8*)(nb + boff + n * 512);
#pragma unroll
    for (int j = 0; j < 4; ++j) afn[j] = *(const bf16x8*)(nb + aoff + j * 512);
  }
  __builtin_amdgcn_s_setprio(1);
#pragma unroll
  for (int j = 0; j < 4; ++j)
#pragma unroll
    for (int n = 0; n < 4; ++n)
      acc[j][n] = __builtin_amdgcn_mfma_f32_16x16x32_bf16(afc[j], bfc[n], acc[j][n], 0, 0, 0);
  __builtin_amdgcn_s_setprio(0);
  if (stg) { gload16(Asrc + (size_t)128 * DIM + kc, stgd + 4096);
             gload16(Bsrc + (size_t)128 * DIM + kc, stgd + 8192 + 4096); }
  if (pre) {
#pragma unroll
    for (int j = 0; j < 4; ++j) afn[4 + j] = *(const bf16x8*)(nb + aoff + 2048 + j * 512);
  }
  __builtin_amdgcn_s_setprio(1);
#pragma unroll
  for (int j = 0; j < 4; ++j)
#pragma unroll
    for (int n = 0; n < 4; ++n)
      acc[4 + j][n] = __builtin_amdgcn_mfma_f32_16x16x32_bf16(afc[4 + j], bfc[n], acc[4 + j][n], 0, 0, 0);
  __builtin_amdgcn_s_setprio(0);
  if (kt < NT - 3)       { asm volatile("s_waitcnt vmcnt(4)" ::: "memory"); }
  else if (kt == NT - 3) { asm volatile("s_waitcnt vmcnt(0)" ::: "memory"); }
  __builtin_amdgcn_s_barrier();
}

__device__ __forceinline__ void gemm256_mainloop(const short* __restrict__ A,
                                                 const short* __restrict__ Bw,
                                                 int tm, int tn, short* lds, f32x4 (&acc)[8][4]) {
  const int tid = threadIdx.x;
  const int srow = tid >> 2;
  const int sslot = ((tid & 3) - (tid >> 3)) & 3;
  const int l = tid & 63, lr = l & 15, lg = l >> 4;
  const int w = tid >> 6, wm = w >> 2, wn = w & 3;
  const short* Asrc = A + (size_t)(tm * 256 + srow) * DIM + sslot * 8;
  const short* Bsrc = Bw + (size_t)(tn * 256 + srow) * DIM + sslot * 8;
  short* sdst = lds + tid * 8;
  const int slotR = (lg + (lr >> 1)) & 3;
  const int aoff = wm * 4096 + lr * 32 + slotR * 8;
  const int boff = 8192 + (wn >> 1) * 4096 + ((wn & 1) * 64 + lr) * 32 + slotR * 8;
#pragma unroll
  for (int m = 0; m < 8; ++m)
#pragma unroll
    for (int n = 0; n < 4; ++n) { f32x4 z = {0.f, 0.f, 0.f, 0.f}; acc[m][n] = z; }

#pragma unroll
  for (int kt = 0; kt < 3; ++kt) {
    gload16(Asrc + kt * 32, sdst + kt * 16384);
    gload16(Bsrc + kt * 32, sdst + kt * 16384 + 8192);
    gload16(Asrc + (size_t)128 * DIM + kt * 32, sdst + kt * 16384 + 4096);
    gload16(Bsrc + (size_t)128 * DIM + kt * 32, sdst + kt * 16384 + 8192 + 4096);
  }
  asm volatile("s_waitcnt vmcnt(4)" ::: "memory");
  __builtin_amdgcn_s_barrier();

  bf16x8 afA[8], bfA[4], afB[8], bfB[4];
#pragma unroll
  for (int n = 0; n < 4; ++n) bfA[n] = *(const bf16x8*)(lds + boff + n * 512);
#pragma unroll
  for (int j = 0; j < 4; ++j) afA[j] = *(const bf16x8*)(lds + aoff + j * 512);
#pragma unroll
  for (int j = 0; j < 4; ++j) afA[4 + j] = *(const bf16x8*)(lds + aoff + 2048 + j * 512);

  for (int kt = 0; kt < NT; kt += 2) {
    tile_step(kt,     lds, Asrc, Bsrc, sdst, aoff, boff, afA, bfA, afB, bfB, acc);
    tile_step(kt + 1, lds, Asrc, Bsrc, sdst, aoff, boff, afB, bfB, afA, bfA, acc);
  }
}

// ---------------- QKV GEMM: 256^2 ring + LDS-staged coalesced epilogue (round-10) ----------------
__global__ __launch_bounds__(512, 2)
void gemm_qkv_kernel(const short* __restrict__ xb, const short* __restrict__ wqb,
                     const float* __restrict__ q_bias, const float* __restrict__ v_bias,
                     short* __restrict__ qkvb) {
  __shared__ __attribute__((aligned(16))) short lds[65536];   // 128 KB
  const int wg = xcd_swz(blockIdx.x, 50 * 9);
  const int tn = wg % 9, tm = wg / 9;
  f32x4 acc[8][4];
  gemm256_mainloop(xb, wqb, tm, tn, lds, acc);

  const int tid = threadIdx.x;
  const int w = tid >> 6, wm = w >> 2, wn = w & 3;
  const int l = tid & 63, lr = l & 15, lg = l >> 4;
  const int cbase = tn * 256 + wn * 64;
  for (int half = 0; half < 2; ++half) {
    if (wm == half) {
#pragma unroll
      for (int n = 0; n < 4; ++n) {
        int c = cbase + n * 16 + lr;
        int part = (c < 768) ? 0 : ((c < 1536) ? 1 : 2);
        float bias = (part == 0) ? q_bias[c] : ((part == 2) ? v_bias[c - 1536] : 0.f);
        float scl = (part == 0) ? 0.125f : 1.f;
#pragma unroll
        for (int m = 0; m < 8; ++m)
#pragma unroll
          for (int i = 0; i < 4; ++i)
            lds[(m * 16 + lg * 4 + i) * 264 + wn * 64 + n * 16 + lr] =
                f2bf((acc[m][n][i] + bias) * scl);
      }
    }
    __syncthreads();
#pragma unroll
    for (int p = 0; p < 8; ++p) {
      int chunk = tid + p * 512;
      int row = chunk >> 5, ch = chunk & 31;
      bf16x8 v = *(const bf16x8*)(lds + row * 264 + ch * 8);
      *(bf16x8*)(qkvb + (size_t)(tm * 256 + half * 128 + row) * QKVD + tn * 256 + ch * 8) = v;
    }
    __syncthreads();
  }
}

// ======== 128x128 ring GEMM core (proj; round-10 proven) ========
__device__ __forceinline__ void tile_step128(int kt, short* lds,
                                             const short* Asrc, const short* Bsrc, short* sdst,
                                             int aoff, int boff,
                                             bf16x8 (&afc)[4], bf16x8 (&bfc)[4],
                                             bf16x8 (&afn)[4], bf16x8 (&bfn)[4],
                                             f32x4 (&acc)[4][4]) {
  const bool stg = (kt < NT - 3);
  const bool pre = (kt < NT - 1);
  const short* nb = lds + ((kt + 1) & 3) * 8192;
  short* stgd = sdst + ((kt + 3) & 3) * 8192;
  const int kc = (kt + 3) * 32;
  if (stg) { gload16(Asrc + kc, stgd); gload16(Bsrc + kc, stgd + 4096); }
  if (pre) {
#pragma unroll
    for (int n = 0; n < 4; ++n) bfn[n] = *(const bf16x8*)(nb + boff + n * 512);
#pragma unroll
    for (int j = 0; j < 2; ++j) afn[j] = *(const bf16x8*)(nb + aoff + j * 512);
  }
  __builtin_amdgcn_s_setprio(1);
#pragma unroll
  for (int j = 0; j < 2; ++j)
#pragma unroll
    for (int n = 0; n < 4; ++n)
      acc[j][n] = __builtin_amdgcn_mfma_f32_16x16x32_bf16(afc[j], bfc[n], acc[j][n], 0, 0, 0);
  __builtin_amdgcn_s_setprio(0);
  if (stg) { gload16(Asrc + (size_t)64 * DIM + kc, stgd + 2048);
             gload16(Bsrc + (size_t)64 * DIM + kc, stgd + 4096 + 2048); }
  if (pre) {
#pragma unroll
    for (int j = 2; j < 4; ++j) afn[j] = *(const bf16x8*)(nb + aoff + j * 512);
  }
  __builtin_amdgcn_s_setprio(1);
#pragma unroll
  for (int j = 2; j < 4; ++j)
#pragma unroll
    for (int n = 0; n < 4; ++n)
      acc[j][n] = __builtin_amdgcn_mfma_f32_16x16x32_bf16(afc[j], bfc[n], acc[j][n], 0, 0, 0);
  __builtin_amdgcn_s_setprio(0);
  if (kt < NT - 3)       { asm volatile("s_waitcnt vmcnt(4)" ::: "memory"); }
  else if (kt == NT - 3) { asm volatile("s_waitcnt vmcnt(0)" ::: "memory"); }
  __builtin_amdgcn_s_barrier();
}

__global__ __launch_bounds__(256, 2)
void gemm_proj_kernel(const short* __restrict__ ab, const short* __restrict__ wpb,
                      const float* __restrict__ proj_bias, float* __restrict__ out) {
  __shared__ __attribute__((aligned(16))) short lds[32768];   // 64 KB
  const int wg = xcd_swz(blockIdx.x, 99 * 6);
  const int tn = wg % 6, tm = wg / 6;
  const int tid = threadIdx.x;
  const int srow = tid >> 2;
  const int sslot = ((tid & 3) - (tid >> 3)) & 3;
  const int l = tid & 63, lr = l & 15, lg = l >> 4;
  const int w = tid >> 6, wm = w >> 1, wn = w & 1;
  const short* Asrc = ab + (size_t)(tm * 128 + srow) * DIM + sslot * 8;
  const short* Bsrc = wpb + (size_t)(tn * 128 + srow) * DIM + sslot * 8;
  short* sdst = lds + tid * 8;
  const int slotR = (lg + (lr >> 1)) & 3;
  const int aoff = wm * 2048 + lr * 32 + slotR * 8;
  const int boff = 4096 + wn * 2048 + lr * 32 + slotR * 8;
  f32x4 acc[4][4];
#pragma unroll
  for (int m = 0; m < 4; ++m)
#pragma unroll
    for (int n = 0; n < 4; ++n) { f32x4 z = {0.f, 0.f, 0.f, 0.f}; acc[m][n] = z; }

#pragma unroll
  for (int kt = 0; kt < 3; ++kt) {
    gload16(Asrc + kt * 32, sdst + kt * 8192);
    gload16(Bsrc + kt * 32, sdst + kt * 8192 + 4096);
    gload16(Asrc + (size_t)64 * DIM + kt * 32, sdst + kt * 8192 + 2048);
    gload16(Bsrc + (size_t)64 * DIM + kt * 32, sdst + kt * 8192 + 4096 + 2048);
  }
  asm volatile("s_waitcnt vmcnt(4)" ::: "memory");
  __builtin_amdgcn_s_barrier();

  bf16x8 afA[4], bfA[4], afB[4], bfB[4];
#pragma unroll
  for (int n = 0; n < 4; ++n) bfA[n] = *(const bf16x8*)(lds + boff + n * 512);
#pragma unroll
  for (int j = 0; j < 4; ++j) afA[j] = *(const bf16x8*)(lds + aoff + j * 512);

  for (int kt = 0; kt < NT; kt += 2) {
    tile_step128(kt,     lds, Asrc, Bsrc, sdst, aoff, boff, afA, bfA, afB, bfB, acc);
    tile_step128(kt + 1, lds, Asrc, Bsrc, sdst, aoff, boff, afB, bfB, afA, bfA, acc);
  }

  float* ldsF = (float*)lds;
  for (int p = 0; p < 2; ++p) {
    if (wm == p) {
#pragma unroll
      for (int n = 0; n < 4; ++n) {
        int c = tn * 128 + wn * 64 + n * 16 + lr;
        float pb = proj_bias[c];
#pragma unroll
        for (int m = 0; m < 4; ++m)
#pragma unroll
          for (int i = 0; i < 4; ++i)
            ldsF[(m * 16 + lg * 4 + i) * 132 + wn * 64 + n * 16 + lr] = acc[m][n][i] + pb;
      }
    }
    __syncthreads();
#pragma unroll
    for (int k = 0; k < 8; ++k) {
      int chunk = tid + k * 256;
      int row = chunk >> 5, ch = chunk & 31;
      int r = tm * 128 + p * 64 + row;
      if (r < M_ROWS) {
        f32x4 v = *(const f32x4*)(ldsF + row * 132 + ch * 4);
        *(f32x4*)(out + (size_t)r * DIM + tn * 128 + ch * 4) = v;
      }
    }
    __syncthreads();
  }
}

// ------- attention: round-10 8-wave structure + gload16 V staging + coalesced O stores -------
__global__ __launch_bounds__(512, 1)
void attn_kernel(const short* __restrict__ qkvb, const float* __restrict__ rpbf,
                 short* __restrict__ aout) {
  __shared__ __attribute__((aligned(16))) short Klds[208 * 64];
  __shared__ __attribute__((aligned(16))) short Vlds[64 * NPS];
  __shared__ __attribute__((aligned(16))) short Plds[8 * 16 * NPS];  // also V row-major scratch
  const int bh = blockIdx.x;
  const int b = bh / 12, h = bh - b * 12;
  const short* base = qkvb + (size_t)(b * 197) * QKVD;
  const short* Qg = base + h * 64;
  const short* Kg = base + 768 + h * 64;
  const short* Vg = base + 1536 + h * 64;
  const float* RP = rpbf + (size_t)h * NP * NP;
  const int tid = threadIdx.x;
  const int wave = tid >> 6, l = tid & 63, lr = l & 15, lg = l >> 4;

  // stage K swizzled + V row-major (both via global_load_lds, pipelined together)
  for (int c = tid; c < 1664; c += 512) {
    int r = c >> 3, sp = c & 7;
    int rr = r < NTOK ? r : NTOK - 1;
    gload16(Kg + (size_t)rr * QKVD + ((sp ^ (r & 7)) << 3), Klds + c * 8);
    gload16(Vg + (size_t)rr * QKVD + sp * 8, Plds + c * 8);   // Plds[t][64] scratch
  }
  __syncthreads();
  // transpose V: Plds[t][64] -> Vlds[d][t]  (b128 reads, b16 writes at LDS speed)
  for (int c = tid; c < 1664; c += 512) {
    int t = c >> 3, j = c & 7;
    bf16x8 tv = *(const bf16x8*)(Plds + t * 64 + j * 8);
#pragma unroll
    for (int e = 0; e < 8; ++e)
      Vlds[(j * 8 + e) * NPS + t] = tv[e];
  }
  if (tid < 64) {
    for (int j = NP; j < NPS; ++j) Vlds[tid * NPS + j] = 0;  // pad cols of V^T
  }
  __syncthreads();

  short* Pw = Plds + wave * 16 * NPS;
  for (int s = wave; s < 13; s += 8) {
    const int row0 = s * 16;
    const int qrow = (row0 + lr < NTOK) ? (row0 + lr) : (NTOK - 1);
    bf16x8 qf0 = *(const bf16x8*)(Qg + (size_t)qrow * QKVD + lg * 8);
    bf16x8 qf1 = *(const bf16x8*)(Qg + (size_t)qrow * QKVD + 32 + lg * 8);
    f32x4 acc[13];
#pragma unroll
    for (int t = 0; t < 13; ++t) { f32x4 z = {0.f, 0.f, 0.f, 0.f}; acc[t] = z; }
    __builtin_amdgcn_s_setprio(1);
#pragma unroll
    for (int t = 0; t < 13; ++t) {
      int rk = t * 16 + lr;
      int sw = lr & 7;
      bf16x8 kf0 = *(const bf16x8*)(Klds + rk * 64 + ((lg ^ sw) << 3));
      bf16x8 kf1 = *(const bf16x8*)(Klds + rk * 64 + (((4 + lg) ^ sw) << 3));
      acc[t] = __builtin_amdgcn_mfma_f32_16x16x32_bf16(qf0, kf0, acc[t], 0, 0, 0);
      acc[t] = __builtin_amdgcn_mfma_f32_16x16x32_bf16(qf1, kf1, acc[t], 0, 0, 0);
    }
    __builtin_amdgcn_s_setprio(0);
    float sum4[4];
#pragma unroll
    for (int i = 0; i < 4; ++i) {
      const int row = row0 + lg * 4 + i;
      const float* rp = RP + (size_t)row * NP;
      float sv[13];
      float mx = -3e38f;
#pragma unroll
      for (int t = 0; t < 13; ++t) {
        int col = t * 16 + lr;
        float s_ = (col < NTOK) ? (acc[t][i] + rp[col]) : -3e38f;
        sv[t] = s_;
        mx = fmaxf(mx, s_);
      }
      mx = fmaxf(mx, __shfl_xor(mx, 1, 16));
      mx = fmaxf(mx, __shfl_xor(mx, 2, 16));
      mx = fmaxf(mx, __shfl_xor(mx, 4, 16));
      mx = fmaxf(mx, __shfl_xor(mx, 8, 16));
      float sm = 0.f;
#pragma unroll
      for (int t = 0; t < 13; ++t) {
        float p = __expf(sv[t] - mx);
        sm += p;
        Pw[(lg * 4 + i) * NPS + t * 16 + lr] = f2bf(p);
      }
      sm += __shfl_xor(sm, 1, 16);
      sm += __shfl_xor(sm, 2, 16);
      sm += __shfl_xor(sm, 4, 16);
      sm += __shfl_xor(sm, 8, 16);
      sum4[i] = sm;
      Pw[(lg * 4 + i) * NPS + 208 + lr] = 0;
    }
    f32x4 o[4];
#pragma unroll
    for (int dt = 0; dt < 4; ++dt) { f32x4 z = {0.f, 0.f, 0.f, 0.f}; o[dt] = z; }
    __builtin_amdgcn_s_setprio(1);
#pragma unroll
    for (int jb = 0; jb < 7; ++jb) {
      bf16x8 pf = *(const bf16x8*)(Pw + lr * NPS + jb * 32 + lg * 8);
#pragma unroll
      for (int dt = 0; dt < 4; ++dt) {
        bf16x8 vf = *(const bf16x8*)(Vlds + (dt * 16 + lr) * NPS + jb * 32 + lg * 8);
        o[dt] = __builtin_amdgcn_mfma_f32_16x16x32_bf16(pf, vf, o[dt], 0, 0, 0);
      }
    }
    __builtin_amdgcn_s_setprio(0);
    // ---- O: stage in Pw (wave-local, no barrier), then coalesced bf16x8 stores ----
#pragma unroll
    for (int i = 0; i < 4; ++i) {
      float inv = 1.f / sum4[i];
#pragma unroll
      for (int dt = 0; dt < 4; ++dt)
        Pw[(lg * 4 + i) * NPS + dt * 16 + lr] = f2bf(o[dt][i] * inv);
    }
#pragma unroll
    for (int r8 = 0; r8 < 2; ++r8) {
      int chunk = l + r8 * 64;
      int row = chunk >> 3, ch = chunk & 7;
      int grow = row0 + row;
      if (grow < NTOK) {
        bf16x8 v = *(const bf16x8*)(Pw + row * NPS + ch * 8);
        *(bf16x8*)(aout + (size_t)(b * 197 + grow) * DIM + h * 64 + ch * 8) = v;
      }
    }
  }
}

extern "C" void kernel_launch(void* const* d_in, const int* in_sizes, int n_in,
                              void* d_out, int out_size, void* d_ws, size_t ws_size,
                              hipStream_t stream) {
  const float* x         = (const float*)d_in[0];
  const float* wqkv      = (const float*)d_in[1];
  const float* q_bias    = (const float*)d_in[2];
  const float* v_bias    = (const float*)d_in[3];
  const float* table     = (const float*)d_in[4];
  const float* wproj     = (const float*)d_in[5];
  const float* proj_bias = (const float*)d_in[6];
  float* out = (float*)d_out;

  char* p = (char*)d_ws;
  short* xb    = (short*)p; p += (size_t)M_PAD * DIM * 2;
  short* wqb   = (short*)p; p += (size_t)3 * DIM * DIM * 2;
  short* wpb   = (short*)p; p += (size_t)DIM * DIM * 2;
  short* qkvb  = (short*)p; p += (size_t)M_PAD * QKVD * 2;
  float* rpbf  = (float*)p; p += (size_t)NHEADS * NP * NP * 4;
  short* aout  = xb;  // reuse: xb is dead after gemm_qkv (pad rows stay zero)

  const int conv_tot = (M_ROWS * DIM + 3 * DIM * DIM + DIM * DIM + (M_PAD - M_ROWS) * DIM) / 4;
  const int prep_tot = conv_tot + NHEADS * NP * NP;
  prep_kernel<<<(prep_tot + 255) / 256, 256, 0, stream>>>(x, wqkv, wproj, table, xb, wqb, wpb, rpbf);
  gemm_qkv_kernel<<<50 * 9, 512, 0, stream>>>(xb, wqb, q_bias, v_bias, qkvb);
  attn_kernel<<<HEADS_TOT, 512, 0, stream>>>(qkvb, rpbf, aout);
  gemm_proj_kernel<<<99 * 6, 256, 0, stream>>>(aout, wpb, proj_bias, out);
}

// Round 14
// 141.468 us; speedup vs baseline: 1.0672x; 1.0108x over previous
//
#include <hip/hip_runtime.h>
#include <hip/hip_bf16.h>

#define DIM 768
#define QKVD 2304      // 3*DIM
#define NHEADS 12
#define NTOK 197
#define NP 208         // padded tokens (13*16)
#define NPS 232        // VT / P LDS row stride in shorts
#define M_ROWS 12608   // B*N
#define M_PAD 12800    // 100*128 = 50*256
#define HEADS_TOT 768  // B*H
#define NT 24          // K-tiles of 32 (768/32)

typedef __attribute__((ext_vector_type(8))) short bf16x8;
typedef __attribute__((ext_vector_type(4))) float f32x4;

__device__ inline short f2bf(float f) {
  union { __hip_bfloat16 h; short s; } u;
  u.h = __float2bfloat16(f);
  return u.s;
}

__device__ __forceinline__ void gload16(const short* g, short* l) {
  __builtin_amdgcn_global_load_lds((const __attribute__((address_space(1))) void*)g,
                                   (__attribute__((address_space(3))) void*)l, 16, 0, 0);
}

// bijective XCD-aware swizzle (m204)
__device__ __forceinline__ int xcd_swz(int orig, int nwg) {
  int q = nwg >> 3, r = nwg & 7;
  int x = orig & 7, p = orig >> 3;
  return (x < r ? x * (q + 1) : r * (q + 1) + (x - r) * q) + p;
}

// ---------------- prep: fp32->bf16 converts + xb pad zero + TRANSPOSED rpb expansion ----------------
// rpbf layout: [h][col][row] fp32 (transposed) -> attn loads 4 consecutive rows as f32x4.
__global__ void prep_kernel(const float* __restrict__ x, const float* __restrict__ wq,
                            const float* __restrict__ wp, const float* __restrict__ table,
                            short* __restrict__ xb, short* __restrict__ wqb,
                            short* __restrict__ wpb, float* __restrict__ rpbf) {
  int idx = blockIdx.x * 256 + threadIdx.x;
  const int n_x  = M_ROWS * DIM / 4;
  const int n_wq = 3 * DIM * DIM / 4;
  const int n_wp = DIM * DIM / 4;
  const int n_pad = (M_PAD - M_ROWS) * DIM / 4;
  const int conv_tot = n_x + n_wq + n_wp + n_pad;
  if (idx < conv_tot) {
    if (idx >= n_x + n_wq + n_wp) {
      int k = idx - n_x - n_wq - n_wp;
      short4 z = {0, 0, 0, 0};
      *(short4*)(xb + (size_t)M_ROWS * DIM + (size_t)k * 4) = z;
      return;
    }
    const float4* src; short* dst; int off;
    if (idx < n_x)             { src = (const float4*)x;  dst = xb;  off = idx; }
    else if (idx < n_x + n_wq) { src = (const float4*)wq; dst = wqb; off = idx - n_x; }
    else                       { src = (const float4*)wp; dst = wpb; off = idx - n_x - n_wq; }
    float4 v = src[off];
    short4 o;
    o.x = f2bf(v.x); o.y = f2bf(v.y); o.z = f2bf(v.z); o.w = f2bf(v.w);
    *(short4*)(dst + (size_t)off * 4) = o;
    return;
  }
  int ridx = idx - conv_tot;
  if (ridx >= NHEADS * NP * NP) return;
  int h = ridx / (NP * NP);
  int rem = ridx - h * NP * NP;
  int j = rem / NP;          // col (outer dim of transposed layout)
  int i = rem - j * NP;      // row (fastest -> coalesced write)
  float v = 0.f;
  if (i < NTOK && j < NTOK) {
    int t;
    if (i == 0 && j == 0) t = 731;
    else if (i == 0)      t = 729;
    else if (j == 0)      t = 730;
    else {
      int p = i - 1, q = j - 1;
      int ri = p / 14, ci = p - ri * 14;
      int rj = q / 14, cj = q - rj * 14;
      t = (ri - rj + 13) * 27 + (ci - cj + 13);
    }
    v = table[t * NHEADS + h];
  }
  rpbf[ridx] = v;   // rpbf[h][j][i] = bias(row=i, col=j)
}

// ================= 256x256 ring GEMM (round-10 proven: 57us, 0 conflicts) =================
__device__ __forceinline__ void tile_step(int kt, short* lds,
                                          const short* Asrc, const short* Bsrc, short* sdst,
                                          int aoff, int boff,
                                          bf16x8 (&afc)[8], bf16x8 (&bfc)[4],
                                          bf16x8 (&afn)[8], bf16x8 (&bfn)[4],
                                          f32x4 (&acc)[8][4]) {
  const bool stg = (kt < NT - 3);
  const bool pre = (kt < NT - 1);
  const short* nb = lds + ((kt + 1) & 3) * 16384;
  short* stgd = sdst + ((kt + 3) & 3) * 16384;
  const int kc = (kt + 3) * 32;
  if (stg) { gload16(Asrc + kc, stgd); gload16(Bsrc + kc, stgd + 8192); }
  if (pre) {
#pragma unroll
    for (int n = 0; n < 4; ++n) bfn[n] = *(const bf16x8*)(nb + boff + n * 512);
#pragma unroll
    for (int j = 0; j < 4; ++j) afn[j] = *(const bf16x8*)(nb + aoff + j * 512);
  }
  __builtin_amdgcn_s_setprio(1);
#pragma unroll
  for (int j = 0; j < 4; ++j)
#pragma unroll
    for (int n = 0; n < 4; ++n)
      acc[j][n] = __builtin_amdgcn_mfma_f32_16x16x32_bf16(afc[j], bfc[n], acc[j][n], 0, 0, 0);
  __builtin_amdgcn_s_setprio(0);
  if (stg) { gload16(Asrc + (size_t)128 * DIM + kc, stgd + 4096);
             gload16(Bsrc + (size_t)128 * DIM + kc, stgd + 8192 + 4096); }
  if (pre) {
#pragma unroll
    for (int j = 0; j < 4; ++j) afn[4 + j] = *(const bf16x8*)(nb + aoff + 2048 + j * 512);
  }
  __builtin_amdgcn_s_setprio(1);
#pragma unroll
  for (int j = 0; j < 4; ++j)
#pragma unroll
    for (int n = 0; n < 4; ++n)
      acc[4 + j][n] = __builtin_amdgcn_mfma_f32_16x16x32_bf16(afc[4 + j], bfc[n], acc[4 + j][n], 0, 0, 0);
  __builtin_amdgcn_s_setprio(0);
  if (kt < NT - 3)       { asm volatile("s_waitcnt vmcnt(4)" ::: "memory"); }
  else if (kt == NT - 3) { asm volatile("s_waitcnt vmcnt(0)" ::: "memory"); }
  __builtin_amdgcn_s_barrier();
}

__device__ __forceinline__ void gemm256_mainloop(const short* __restrict__ A,
                                                 const short* __restrict__ Bw,
                                                 int tm, int tn, short* lds, f32x4 (&acc)[8][4]) {
  const int tid = threadIdx.x;
  const int srow = tid >> 2;
  const int sslot = ((tid & 3) - (tid >> 3)) & 3;
  const int l = tid & 63, lr = l & 15, lg = l >> 4;
  const int w = tid >> 6, wm = w >> 2, wn = w & 3;
  const short* Asrc = A + (size_t)(tm * 256 + srow) * DIM + sslot * 8;
  const short* Bsrc = Bw + (size_t)(tn * 256 + srow) * DIM + sslot * 8;
  short* sdst = lds + tid * 8;
  const int slotR = (lg + (lr >> 1)) & 3;
  const int aoff = wm * 4096 + lr * 32 + slotR * 8;
  const int boff = 8192 + (wn >> 1) * 4096 + ((wn & 1) * 64 + lr) * 32 + slotR * 8;
#pragma unroll
  for (int m = 0; m < 8; ++m)
#pragma unroll
    for (int n = 0; n < 4; ++n) { f32x4 z = {0.f, 0.f, 0.f, 0.f}; acc[m][n] = z; }

#pragma unroll
  for (int kt = 0; kt < 3; ++kt) {
    gload16(Asrc + kt * 32, sdst + kt * 16384);
    gload16(Bsrc + kt * 32, sdst + kt * 16384 + 8192);
    gload16(Asrc + (size_t)128 * DIM + kt * 32, sdst + kt * 16384 + 4096);
    gload16(Bsrc + (size_t)128 * DIM + kt * 32, sdst + kt * 16384 + 8192 + 4096);
  }
  asm volatile("s_waitcnt vmcnt(4)" ::: "memory");
  __builtin_amdgcn_s_barrier();

  bf16x8 afA[8], bfA[4], afB[8], bfB[4];
#pragma unroll
  for (int n = 0; n < 4; ++n) bfA[n] = *(const bf16x8*)(lds + boff + n * 512);
#pragma unroll
  for (int j = 0; j < 4; ++j) afA[j] = *(const bf16x8*)(lds + aoff + j * 512);
#pragma unroll
  for (int j = 0; j < 4; ++j) afA[4 + j] = *(const bf16x8*)(lds + aoff + 2048 + j * 512);

  for (int kt = 0; kt < NT; kt += 2) {
    tile_step(kt,     lds, Asrc, Bsrc, sdst, aoff, boff, afA, bfA, afB, bfB, acc);
    tile_step(kt + 1, lds, Asrc, Bsrc, sdst, aoff, boff, afB, bfB, afA, bfA, acc);
  }
}

// ---------------- QKV GEMM: 256^2 ring + LDS-staged coalesced epilogue (round-10) ----------------
__global__ __launch_bounds__(512, 2)
void gemm_qkv_kernel(const short* __restrict__ xb, const short* __restrict__ wqb,
                     const float* __restrict__ q_bias, const float* __restrict__ v_bias,
                     short* __restrict__ qkvb) {
  __shared__ __attribute__((aligned(16))) short lds[65536];   // 128 KB
  const int wg = xcd_swz(blockIdx.x, 50 * 9);
  const int tn = wg % 9, tm = wg / 9;
  f32x4 acc[8][4];
  gemm256_mainloop(xb, wqb, tm, tn, lds, acc);

  const int tid = threadIdx.x;
  const int w = tid >> 6, wm = w >> 2, wn = w & 3;
  const int l = tid & 63, lr = l & 15, lg = l >> 4;
  const int cbase = tn * 256 + wn * 64;
  for (int half = 0; half < 2; ++half) {
    if (wm == half) {
#pragma unroll
      for (int n = 0; n < 4; ++n) {
        int c = cbase + n * 16 + lr;
        int part = (c < 768) ? 0 : ((c < 1536) ? 1 : 2);
        float bias = (part == 0) ? q_bias[c] : ((part == 2) ? v_bias[c - 1536] : 0.f);
        float scl = (part == 0) ? 0.125f : 1.f;
#pragma unroll
        for (int m = 0; m < 8; ++m)
#pragma unroll
          for (int i = 0; i < 4; ++i)
            lds[(m * 16 + lg * 4 + i) * 264 + wn * 64 + n * 16 + lr] =
                f2bf((acc[m][n][i] + bias) * scl);
      }
    }
    __syncthreads();
#pragma unroll
    for (int p = 0; p < 8; ++p) {
      int chunk = tid + p * 512;
      int row = chunk >> 5, ch = chunk & 31;
      bf16x8 v = *(const bf16x8*)(lds + row * 264 + ch * 8);
      *(bf16x8*)(qkvb + (size_t)(tm * 256 + half * 128 + row) * QKVD + tn * 256 + ch * 8) = v;
    }
    __syncthreads();
  }
}

// ======== 128x128 ring GEMM core (proj; round-10 proven) ========
__device__ __forceinline__ void tile_step128(int kt, short* lds,
                                             const short* Asrc, const short* Bsrc, short* sdst,
                                             int aoff, int boff,
                                             bf16x8 (&afc)[4], bf16x8 (&bfc)[4],
                                             bf16x8 (&afn)[4], bf16x8 (&bfn)[4],
                                             f32x4 (&acc)[4][4]) {
  const bool stg = (kt < NT - 3);
  const bool pre = (kt < NT - 1);
  const short* nb = lds + ((kt + 1) & 3) * 8192;
  short* stgd = sdst + ((kt + 3) & 3) * 8192;
  const int kc = (kt + 3) * 32;
  if (stg) { gload16(Asrc + kc, stgd); gload16(Bsrc + kc, stgd + 4096); }
  if (pre) {
#pragma unroll
    for (int n = 0; n < 4; ++n) bfn[n] = *(const bf16x8*)(nb + boff + n * 512);
#pragma unroll
    for (int j = 0; j < 2; ++j) afn[j] = *(const bf16x8*)(nb + aoff + j * 512);
  }
  __builtin_amdgcn_s_setprio(1);
#pragma unroll
  for (int j = 0; j < 2; ++j)
#pragma unroll
    for (int n = 0; n < 4; ++n)
      acc[j][n] = __builtin_amdgcn_mfma_f32_16x16x32_bf16(afc[j], bfc[n], acc[j][n], 0, 0, 0);
  __builtin_amdgcn_s_setprio(0);
  if (stg) { gload16(Asrc + (size_t)64 * DIM + kc, stgd + 2048);
             gload16(Bsrc + (size_t)64 * DIM + kc, stgd + 4096 + 2048); }
  if (pre) {
#pragma unroll
    for (int j = 2; j < 4; ++j) afn[j] = *(const bf16x8*)(nb + aoff + j * 512);
  }
  __builtin_amdgcn_s_setprio(1);
#pragma unroll
  for (int j = 2; j < 4; ++j)
#pragma unroll
    for (int n = 0; n < 4; ++n)
      acc[j][n] = __builtin_amdgcn_mfma_f32_16x16x32_bf16(afc[j], bfc[n], acc[j][n], 0, 0, 0);
  __builtin_amdgcn_s_setprio(0);
  if (kt < NT - 3)       { asm volatile("s_waitcnt vmcnt(4)" ::: "memory"); }
  else if (kt == NT - 3) { asm volatile("s_waitcnt vmcnt(0)" ::: "memory"); }
  __builtin_amdgcn_s_barrier();
}

__global__ __launch_bounds__(256, 2)
void gemm_proj_kernel(const short* __restrict__ ab, const short* __restrict__ wpb,
                      const float* __restrict__ proj_bias, float* __restrict__ out) {
  __shared__ __attribute__((aligned(16))) short lds[32768];   // 64 KB
  const int wg = xcd_swz(blockIdx.x, 99 * 6);
  const int tn = wg % 6, tm = wg / 6;
  const int tid = threadIdx.x;
  const int srow = tid >> 2;
  const int sslot = ((tid & 3) - (tid >> 3)) & 3;
  const int l = tid & 63, lr = l & 15, lg = l >> 4;
  const int w = tid >> 6, wm = w >> 1, wn = w & 1;
  const short* Asrc = ab + (size_t)(tm * 128 + srow) * DIM + sslot * 8;
  const short* Bsrc = wpb + (size_t)(tn * 128 + srow) * DIM + sslot * 8;
  short* sdst = lds + tid * 8;
  const int slotR = (lg + (lr >> 1)) & 3;
  const int aoff = wm * 2048 + lr * 32 + slotR * 8;
  const int boff = 4096 + wn * 2048 + lr * 32 + slotR * 8;
  f32x4 acc[4][4];
#pragma unroll
  for (int m = 0; m < 4; ++m)
#pragma unroll
    for (int n = 0; n < 4; ++n) { f32x4 z = {0.f, 0.f, 0.f, 0.f}; acc[m][n] = z; }

#pragma unroll
  for (int kt = 0; kt < 3; ++kt) {
    gload16(Asrc + kt * 32, sdst + kt * 8192);
    gload16(Bsrc + kt * 32, sdst + kt * 8192 + 4096);
    gload16(Asrc + (size_t)64 * DIM + kt * 32, sdst + kt * 8192 + 2048);
    gload16(Bsrc + (size_t)64 * DIM + kt * 32, sdst + kt * 8192 + 4096 + 2048);
  }
  asm volatile("s_waitcnt vmcnt(4)" ::: "memory");
  __builtin_amdgcn_s_barrier();

  bf16x8 afA[4], bfA[4], afB[4], bfB[4];
#pragma unroll
  for (int n = 0; n < 4; ++n) bfA[n] = *(const bf16x8*)(lds + boff + n * 512);
#pragma unroll
  for (int j = 0; j < 4; ++j) afA[j] = *(const bf16x8*)(lds + aoff + j * 512);

  for (int kt = 0; kt < NT; kt += 2) {
    tile_step128(kt,     lds, Asrc, Bsrc, sdst, aoff, boff, afA, bfA, afB, bfB, acc);
    tile_step128(kt + 1, lds, Asrc, Bsrc, sdst, aoff, boff, afB, bfB, afA, bfA, acc);
  }

  float* ldsF = (float*)lds;
  for (int p = 0; p < 2; ++p) {
    if (wm == p) {
#pragma unroll
      for (int n = 0; n < 4; ++n) {
        int c = tn * 128 + wn * 64 + n * 16 + lr;
        float pb = proj_bias[c];
#pragma unroll
        for (int m = 0; m < 4; ++m)
#pragma unroll
          for (int i = 0; i < 4; ++i)
            ldsF[(m * 16 + lg * 4 + i) * 132 + wn * 64 + n * 16 + lr] = acc[m][n][i] + pb;
      }
    }
    __syncthreads();
#pragma unroll
    for (int k = 0; k < 8; ++k) {
      int chunk = tid + k * 256;
      int row = chunk >> 5, ch = chunk & 31;
      int r = tm * 128 + p * 64 + row;
      if (r < M_ROWS) {
        f32x4 v = *(const f32x4*)(ldsF + row * 132 + ch * 4);
        *(f32x4*)(out + (size_t)r * DIM + tn * 128 + ch * 4) = v;
      }
    }
    __syncthreads();
  }
}

// ---------------- attention: round-10 structure; rpb via transposed f32x4 loads ----------------
__global__ __launch_bounds__(512, 1)
void attn_kernel(const short* __restrict__ qkvb, const float* __restrict__ rpbf,
                 short* __restrict__ aout) {
  __shared__ __attribute__((aligned(16))) short Klds[208 * 64];
  __shared__ __attribute__((aligned(16))) short Vlds[64 * NPS];
  __shared__ __attribute__((aligned(16))) short Plds[8 * 16 * NPS];
  const int bh = blockIdx.x;
  const int b = bh / 12, h = bh - b * 12;
  const short* base = qkvb + (size_t)(b * 197) * QKVD;
  const short* Qg = base + h * 64;
  const short* Kg = base + 768 + h * 64;
  const short* Vg = base + 1536 + h * 64;
  const float* RPT = rpbf + (size_t)h * NP * NP;   // transposed: [col][row]
  const int tid = threadIdx.x;
  const int wave = tid >> 6, l = tid & 63, lr = l & 15, lg = l >> 4;

  for (int c = tid; c < 1664; c += 512) {
    int r = c >> 3, sp = c & 7;
    int rr = r < NTOK ? r : NTOK - 1;
    gload16(Kg + (size_t)rr * QKVD + ((sp ^ (r & 7)) << 3), Klds + c * 8);
  }
  for (int idx = tid; idx < 64 * NP; idx += 512) {
    int t = idx >> 6, d = idx & 63;
    int tt = t < NTOK ? t : NTOK - 1;
    Vlds[d * NPS + t] = Vg[(size_t)tt * QKVD + d];
  }
  __syncthreads();
  if (tid < 64) {
    for (int j = NP; j < NPS; ++j) Vlds[tid * NPS + j] = 0;
  }
  __syncthreads();

  short* Pw = Plds + wave * 16 * NPS;
  for (int s = wave; s < 13; s += 8) {
    const int row0 = s * 16;
    const int qrow = (row0 + lr < NTOK) ? (row0 + lr) : (NTOK - 1);
    bf16x8 qf0 = *(const bf16x8*)(Qg + (size_t)qrow * QKVD + lg * 8);
    bf16x8 qf1 = *(const bf16x8*)(Qg + (size_t)qrow * QKVD + 32 + lg * 8);
    f32x4 acc[13];
#pragma unroll
    for (int t = 0; t < 13; ++t) { f32x4 z = {0.f, 0.f, 0.f, 0.f}; acc[t] = z; }
    __builtin_amdgcn_s_setprio(1);
#pragma unroll
    for (int t = 0; t < 13; ++t) {
      int rk = t * 16 + lr;
      int sw = lr & 7;
      bf16x8 kf0 = *(const bf16x8*)(Klds + rk * 64 + ((lg ^ sw) << 3));
      bf16x8 kf1 = *(const bf16x8*)(Klds + rk * 64 + (((4 + lg) ^ sw) << 3));
      acc[t] = __builtin_amdgcn_mfma_f32_16x16x32_bf16(qf0, kf0, acc[t], 0, 0, 0);
      acc[t] = __builtin_amdgcn_mfma_f32_16x16x32_bf16(qf1, kf1, acc[t], 0, 0, 0);
    }
    __builtin_amdgcn_s_setprio(0);
    // ---- rpb: 13 vectorized f32x4 loads (4 rows per lane for this lane's col) ----
    f32x4 rv[13];
#pragma unroll
    for (int t = 0; t < 13; ++t)
      rv[t] = *(const f32x4*)(RPT + (size_t)(t * 16 + lr) * NP + row0 + lg * 4);
    float sum4[4];
#pragma unroll
    for (int i = 0; i < 4; ++i) {
      float sv[13];
      float mx = -3e38f;
#pragma unroll
      for (int t = 0; t < 13; ++t) {
        int col = t * 16 + lr;
        float s_ = (col < NTOK) ? (acc[t][i] + rv[t][i]) : -3e38f;
        sv[t] = s_;
        mx = fmaxf(mx, s_);
      }
      mx = fmaxf(mx, __shfl_xor(mx, 1, 16));
      mx = fmaxf(mx, __shfl_xor(mx, 2, 16));
      mx = fmaxf(mx, __shfl_xor(mx, 4, 16));
      mx = fmaxf(mx, __shfl_xor(mx, 8, 16));
      float sm = 0.f;
#pragma unroll
      for (int t = 0; t < 13; ++t) {
        float p = __expf(sv[t] - mx);
        sm += p;
        Pw[(lg * 4 + i) * NPS + t * 16 + lr] = f2bf(p);
      }
      sm += __shfl_xor(sm, 1, 16);
      sm += __shfl_xor(sm, 2, 16);
      sm += __shfl_xor(sm, 4, 16);
      sm += __shfl_xor(sm, 8, 16);
      sum4[i] = sm;
      Pw[(lg * 4 + i) * NPS + 208 + lr] = 0;
    }
    f32x4 o[4];
#pragma unroll
    for (int dt = 0; dt < 4; ++dt) { f32x4 z = {0.f, 0.f, 0.f, 0.f}; o[dt] = z; }
    __builtin_amdgcn_s_setprio(1);
#pragma unroll
    for (int jb = 0; jb < 7; ++jb) {
      bf16x8 pf = *(const bf16x8*)(Pw + lr * NPS + jb * 32 + lg * 8);
#pragma unroll
      for (int dt = 0; dt < 4; ++dt) {
        bf16x8 vf = *(const bf16x8*)(Vlds + (dt * 16 + lr) * NPS + jb * 32 + lg * 8);
        o[dt] = __builtin_amdgcn_mfma_f32_16x16x32_bf16(pf, vf, o[dt], 0, 0, 0);
      }
    }
    __builtin_amdgcn_s_setprio(0);
#pragma unroll
    for (int i = 0; i < 4; ++i) {
      const int row = row0 + lg * 4 + i;
      if (row < NTOK) {
        float inv = 1.f / sum4[i];
        size_t base2 = (size_t)(b * 197 + row) * DIM + h * 64;
#pragma unroll
        for (int dt = 0; dt < 4; ++dt)
          aout[base2 + dt * 16 + lr] = f2bf(o[dt][i] * inv);
      }
    }
  }
}

extern "C" void kernel_launch(void* const* d_in, const int* in_sizes, int n_in,
                              void* d_out, int out_size, void* d_ws, size_t ws_size,
                              hipStream_t stream) {
  const float* x         = (const float*)d_in[0];
  const float* wqkv      = (const float*)d_in[1];
  const float* q_bias    = (const float*)d_in[2];
  const float* v_bias    = (const float*)d_in[3];
  const float* table     = (const float*)d_in[4];
  const float* wproj     = (const float*)d_in[5];
  const float* proj_bias = (const float*)d_in[6];
  float* out = (float*)d_out;

  char* p = (char*)d_ws;
  short* xb    = (short*)p; p += (size_t)M_PAD * DIM * 2;
  short* wqb   = (short*)p; p += (size_t)3 * DIM * DIM * 2;
  short* wpb   = (short*)p; p += (size_t)DIM * DIM * 2;
  short* qkvb  = (short*)p; p += (size_t)M_PAD * QKVD * 2;
  float* rpbf  = (float*)p; p += (size_t)NHEADS * NP * NP * 4;
  short* aout  = xb;  // reuse: xb is dead after gemm_qkv (pad rows stay zero)

  const int conv_tot = (M_ROWS * DIM + 3 * DIM * DIM + DIM * DIM + (M_PAD - M_ROWS) * DIM) / 4;
  const int prep_tot = conv_tot + NHEADS * NP * NP;
  prep_kernel<<<(prep_tot + 255) / 256, 256, 0, stream>>>(x, wqkv, wproj, table, xb, wqb, wpb, rpbf);
  gemm_qkv_kernel<<<50 * 9, 512, 0, stream>>>(xb, wqb, q_bias, v_bias, qkvb);
  attn_kernel<<<HEADS_TOT, 512, 0, stream>>>(qkvb, rpbf, aout);
  gemm_proj_kernel<<<99 * 6, 256, 0, stream>>>(aout, wpb, proj_bias, out);
}